// Round 9
// baseline (466.012 us; speedup 1.0000x reference)
//
#include <hip/hip_runtime.h>
#include <cstdint>
#include <cstddef>

// GraphSAGE 3-layer, mean aggregation.
// R9: R8's LDS-free gemm was GRID-limited (3128 waves = 12/CU) with a serial
// load->MFMA chain per k-step (MfmaUtil 12.8%). Re-shaped: wave tile 64x32
// (acc 32 regs), grid 1564 blocks = 6256 waves, launch_bounds(256,4) keeps
// VGPR<=128 for 4 waves/SIMD, plus an explicit 2-stage register pipeline
// (load s+1 while MFMA s — named reg sets, no barriers to block the overlap).
// Block pairs share the A row-panel (bid>>1) for L1/L2 reuse.
// agg (R4/R8 bf16), scan (R3), W hi/lo split (R2) unchanged.

typedef __bf16 bf16x8 __attribute__((ext_vector_type(8)));
typedef __bf16 bf16x4 __attribute__((ext_vector_type(4)));
typedef float  f32x4  __attribute__((ext_vector_type(4)));

static inline size_t align_up(size_t x, size_t a) { return (x + a - 1) / a * a; }

__global__ void deg_kernel(const int* __restrict__ dst, int* __restrict__ deg, int E) {
    int i = blockIdx.x * blockDim.x + threadIdx.x;
    if (i < E) atomicAdd(&deg[dst[i]], 1);
}

// ---- 3-phase scan: deg -> rowptr (exclusive), cursor, inv_deg ----
__global__ void scan_a(const int* __restrict__ deg, int* __restrict__ blocksums, int n) {
    __shared__ int ts[256];
    int t = threadIdx.x;
    int base = blockIdx.x * 1024 + t * 4;
    int s = 0;
    #pragma unroll
    for (int j = 0; j < 4; ++j) if (base + j < n) s += deg[base + j];
    ts[t] = s;
    __syncthreads();
    #pragma unroll
    for (int off = 128; off >= 1; off >>= 1) {
        if (t < off) ts[t] += ts[t + off];
        __syncthreads();
    }
    if (t == 0) blocksums[blockIdx.x] = ts[0];
}

__global__ void scan_b(const int* __restrict__ blocksums, int* __restrict__ blockoff,
                       int NB, int* __restrict__ rowptr_n) {
    __shared__ int ts[256];
    int t = threadIdx.x;
    int v = (t < NB) ? blocksums[t] : 0;
    ts[t] = v;
    __syncthreads();
    for (int off = 1; off < 256; off <<= 1) {
        int u = (t >= off) ? ts[t - off] : 0;
        __syncthreads();
        ts[t] += u;
        __syncthreads();
    }
    if (t < NB) blockoff[t] = ts[t] - v;
    if (t == 255) *rowptr_n = ts[255];
}

__global__ void scan_c(const int* __restrict__ deg, const int* __restrict__ blockoff,
                       int* __restrict__ rowptr, int* __restrict__ cursor,
                       float* __restrict__ inv_deg, int n) {
    __shared__ int ts[256];
    int t = threadIdx.x;
    int base = blockIdx.x * 1024 + t * 4;
    int d[4];
    int s = 0;
    #pragma unroll
    for (int j = 0; j < 4; ++j) {
        d[j] = (base + j < n) ? deg[base + j] : 0;
        s += d[j];
    }
    ts[t] = s;
    __syncthreads();
    for (int off = 1; off < 256; off <<= 1) {
        int u = (t >= off) ? ts[t - off] : 0;
        __syncthreads();
        ts[t] += u;
        __syncthreads();
    }
    int ex = ts[t] - s + blockoff[blockIdx.x];
    #pragma unroll
    for (int j = 0; j < 4; ++j) {
        if (base + j < n) {
            rowptr[base + j] = ex;
            cursor[base + j] = ex;
            inv_deg[base + j] = d[j] > 0 ? 1.0f / (float)d[j] : 0.0f;
            ex += d[j];
        }
    }
}

__global__ void fill_kernel(const int* __restrict__ src, const int* __restrict__ dst,
                            int* __restrict__ cursor, int* __restrict__ csr, int E) {
    int i = blockIdx.x * blockDim.x + threadIdx.x;
    if (i < E) {
        int p = atomicAdd(&cursor[dst[i]], 1);
        csr[p] = src[i];
    }
}

// fp32 -> bf16 (RTNE) convert, 8 elems/thread.
__global__ void f32_to_bf16(const float* __restrict__ in, uint16_t* __restrict__ out, int count) {
    int i = (blockIdx.x * blockDim.x + threadIdx.x) * 8;
    if (i >= count) return;
    float4 v0 = *(const float4*)(in + i);
    float4 v1 = *(const float4*)(in + i + 4);
    bf16x8 o;
    o[0] = (__bf16)v0.x; o[1] = (__bf16)v0.y; o[2] = (__bf16)v0.z; o[3] = (__bf16)v0.w;
    o[4] = (__bf16)v1.x; o[5] = (__bf16)v1.y; o[6] = (__bf16)v1.z; o[7] = (__bf16)v1.w;
    *(bf16x8*)(out + i) = o;
}

__device__ inline void addq(float* a, uint32_t u0, uint32_t u1, uint32_t u2, uint32_t u3) {
    uint32_t u[4] = {u0, u1, u2, u3};
    #pragma unroll
    for (int i = 0; i < 4; ++i) {
        a[2 * i]     += __uint_as_float(u[i] << 16);
        a[2 * i + 1] += __uint_as_float(u[i] & 0xffff0000u);
    }
}

// bf16 gather aggregation: C/8 lanes per node, 16B (8 bf16) per lane.
template<int C>
__global__ void agg_bf16(const uint16_t* __restrict__ hb, const int* __restrict__ rowptr,
                         const int* __restrict__ csr, const float* __restrict__ inv_deg,
                         uint16_t* __restrict__ aggb, int n) {
    constexpr int LPN = C / 8;
    constexpr int NPB = 256 / LPN;
    int node = blockIdx.x * NPB + (int)(threadIdx.x / LPN);
    if (node >= n) return;
    int sub = threadIdx.x % LPN;
    int b = rowptr[node], e = rowptr[node + 1];
    float acc[8] = {0.f, 0.f, 0.f, 0.f, 0.f, 0.f, 0.f, 0.f};
    const uint4* h4 = (const uint4*)hb;
    int k = b;
    for (; k + 3 < e; k += 4) {
        int s0 = csr[k], s1 = csr[k + 1], s2 = csr[k + 2], s3 = csr[k + 3];
        uint4 q0 = h4[(size_t)s0 * LPN + sub];
        uint4 q1 = h4[(size_t)s1 * LPN + sub];
        uint4 q2 = h4[(size_t)s2 * LPN + sub];
        uint4 q3 = h4[(size_t)s3 * LPN + sub];
        addq(acc, q0.x, q0.y, q0.z, q0.w);
        addq(acc, q1.x, q1.y, q1.z, q1.w);
        addq(acc, q2.x, q2.y, q2.z, q2.w);
        addq(acc, q3.x, q3.y, q3.z, q3.w);
    }
    for (; k < e; ++k) {
        uint4 q = h4[(size_t)csr[k] * LPN + sub];
        addq(acc, q.x, q.y, q.z, q.w);
    }
    float id = inv_deg[node];
    bf16x8 o;
    #pragma unroll
    for (int j = 0; j < 8; ++j) o[j] = (__bf16)(acc[j] * id);
    *(bf16x8*)(aggb + (size_t)node * C + sub * 8) = o;
}

// Pre-convert W = [Wl; Wr] into per-k-step bf16 hi/lo planes.
// Step s (BK=32): [hi 16KB][lo 16KB]; element (k,n) at byte n*64 + (k%32)*2.
__global__ void convert_w(const float* __restrict__ Wl, const float* __restrict__ Wr,
                          uint8_t* __restrict__ Wpre, int K1) {
    int n = threadIdx.x;
    int kbase = blockIdx.x * 4;
    bf16x4 hi4, lo4;
    #pragma unroll
    for (int j = 0; j < 4; ++j) {
        int k = kbase + j;
        float w = (k < K1) ? Wl[(size_t)k * 256 + n] : Wr[(size_t)(k - K1) * 256 + n];
        __bf16 h = (__bf16)w;
        __bf16 l = (__bf16)(w - (float)h);
        hi4[j] = h;
        lo4[j] = l;
    }
    int s = kbase >> 5;
    int kk = kbase & 31;
    uint32_t byte = (uint32_t)(n * 64 + kk * 2);
    *(bf16x4*)(Wpre + (size_t)s * 32768 + byte) = hi4;
    *(bf16x4*)(Wpre + (size_t)s * 32768 + 16384 + byte) = lo4;
}

__device__ inline uint16_t f2bf(float f) {
    __bf16 h = (__bf16)f;
    union { __bf16 b; uint16_t u; } c;
    c.b = h;
    return c.u;
}

// LDS-free fused GEMM, 2-stage register pipeline.
// Block = 4 waves; wave tile 64 rows x 32 cols. bid>>1 = row tile (64 rows),
// bid&1 = column half; wave w owns cols (bid&1)*128 + w*32 .. +31.
template<int K1>
__global__ __launch_bounds__(256, 4)
void gemm_direct(const uint16_t* __restrict__ A1, const uint16_t* __restrict__ A2,
                 const uint8_t* __restrict__ Wpre, const float* __restrict__ bias,
                 float* __restrict__ out, uint16_t* __restrict__ outb, int n) {
    constexpr int S1 = K1 / 32;
    constexpr int NT = 2 * S1;          // 8 or 16, even

    const int tid = threadIdx.x;
    const int l = tid & 63;
    const int w = tid >> 6;
    const int lr = l & 15;
    const int lg = l >> 4;
    const int row0 = (blockIdx.x >> 1) * 64;
    const int colbase = (blockIdx.x & 1) * 128 + w * 32;

    f32x4 acc[4][2];
    #pragma unroll
    for (int mt = 0; mt < 4; ++mt)
        #pragma unroll
        for (int nt = 0; nt < 2; ++nt)
            acc[mt][nt] = (f32x4)(0.f);

    size_t aoff[4];
    #pragma unroll
    for (int mt = 0; mt < 4; ++mt)
        aoff[mt] = (size_t)(row0 + mt * 16 + lr) * K1 + lg * 8;

    uint32_t bbyte[2];
    #pragma unroll
    for (int nt = 0; nt < 2; ++nt)
        bbyte[nt] = (uint32_t)((colbase + nt * 16 + lr) * 64 + lg * 16);

    bf16x8 a0_[4], b0h[2], b0l[2], a1_[4], b1h[2], b1l[2];

    auto load = [&](int s, bf16x8 (&af)[4], bf16x8 (&bh)[2], bf16x8 (&bl_)[2]) {
        const uint16_t* __restrict__ A = (s < S1) ? A1 : A2;
        const int kl = ((s < S1) ? s : s - S1) * 32;
        const uint8_t* __restrict__ Ws = Wpre + (size_t)s * 32768;
        #pragma unroll
        for (int mt = 0; mt < 4; ++mt)
            af[mt] = *(const bf16x8*)(A + aoff[mt] + kl);
        #pragma unroll
        for (int nt = 0; nt < 2; ++nt) {
            bh[nt]  = *(const bf16x8*)(Ws + bbyte[nt]);
            bl_[nt] = *(const bf16x8*)(Ws + 16384 + bbyte[nt]);
        }
    };
    auto mfma = [&](bf16x8 (&af)[4], bf16x8 (&bh)[2], bf16x8 (&bl_)[2]) {
        #pragma unroll
        for (int mt = 0; mt < 4; ++mt)
            #pragma unroll
            for (int nt = 0; nt < 2; ++nt) {
                acc[mt][nt] = __builtin_amdgcn_mfma_f32_16x16x32_bf16(af[mt], bh[nt],  acc[mt][nt], 0, 0, 0);
                acc[mt][nt] = __builtin_amdgcn_mfma_f32_16x16x32_bf16(af[mt], bl_[nt], acc[mt][nt], 0, 0, 0);
            }
    };

    load(0, a0_, b0h, b0l);
    #pragma unroll 1
    for (int s = 0; s < NT - 2; s += 2) {
        load(s + 1, a1_, b1h, b1l);
        mfma(a0_, b0h, b0l);
        load(s + 2, a0_, b0h, b0l);
        mfma(a1_, b1h, b1l);
    }
    load(NT - 1, a1_, b1h, b1l);
    mfma(a0_, b0h, b0l);
    mfma(a1_, b1h, b1l);

    // epilogue: D row = mt*16 + lg*4 + rr, col = colbase + nt*16 + lr
    #pragma unroll
    for (int nt = 0; nt < 2; ++nt) {
        int col = colbase + nt * 16 + lr;
        float bv = bias[col];
        #pragma unroll
        for (int mt = 0; mt < 4; ++mt) {
            #pragma unroll
            for (int rr = 0; rr < 4; ++rr) {
                int grow = row0 + mt * 16 + lg * 4 + rr;
                if (grow < n) {
                    float v = fmaxf(acc[mt][nt][rr] + bv, 0.f);
                    if (out)  out[(size_t)grow * 256 + col] = v;
                    if (outb) outb[(size_t)grow * 256 + col] = f2bf(v);
                }
            }
        }
    }
}

extern "C" void kernel_launch(void* const* d_in, const int* in_sizes, int n_in,
                              void* d_out, int out_size, void* d_ws, size_t ws_size,
                              hipStream_t stream) {
    const float* x   = (const float*)d_in[0];
    const int* edge  = (const int*)d_in[1];
    const float* Wl0 = (const float*)d_in[2];
    const float* bl0 = (const float*)d_in[3];
    const float* Wr0 = (const float*)d_in[4];
    const float* Wl1 = (const float*)d_in[5];
    const float* bl1 = (const float*)d_in[6];
    const float* Wr1 = (const float*)d_in[7];
    const float* Wl2 = (const float*)d_in[8];
    const float* bl2 = (const float*)d_in[9];
    const float* Wr2 = (const float*)d_in[10];

    int n = in_sizes[0] / 128;   // 50000
    int E = in_sizes[1] / 2;     // 800000
    int npad = n + 64;
    const int* src = edge;
    const int* dst = edge + E;

    char* wptr = (char*)d_ws;
    auto alloc = [&](size_t bytes) { char* p = wptr; wptr += align_up(bytes, 256); return p; };
    int*      deg    = (int*)alloc((size_t)n * 4);
    int*      rowptr = (int*)alloc(((size_t)n + 1) * 4);
    int*      cursor = (int*)alloc((size_t)n * 4);
    int*      csr    = (int*)alloc((size_t)E * 4);
    float*    invd   = (float*)alloc((size_t)n * 4);
    int*      bsums  = (int*)alloc(256 * 4);
    int*      boff   = (int*)alloc(256 * 4);
    uint8_t*  Wp0    = (uint8_t*)alloc(8 * 32768);
    uint8_t*  Wp1    = (uint8_t*)alloc(16 * 32768);
    uint8_t*  Wp2    = (uint8_t*)alloc(16 * 32768);
    uint16_t* xb     = (uint16_t*)alloc((size_t)npad * 128 * 2);
    uint16_t* aggb   = (uint16_t*)alloc((size_t)npad * 256 * 2);
    uint16_t* h0b    = (uint16_t*)alloc((size_t)npad * 256 * 2);
    uint16_t* h1b    = (uint16_t*)alloc((size_t)npad * 256 * 2);

    int NB = (n + 1023) / 1024;
    hipMemsetAsync(deg, 0, (size_t)n * 4, stream);
    deg_kernel<<<(E + 255) / 256, 256, 0, stream>>>(dst, deg, E);
    scan_a<<<NB, 256, 0, stream>>>(deg, bsums, n);
    scan_b<<<1, 256, 0, stream>>>(bsums, boff, NB, rowptr + n);
    scan_c<<<NB, 256, 0, stream>>>(deg, boff, rowptr, cursor, invd, n);
    fill_kernel<<<(E + 255) / 256, 256, 0, stream>>>(src, dst, cursor, csr, E);

    convert_w<<<2 * 128 / 4, 256, 0, stream>>>(Wl0, Wr0, Wp0, 128);
    convert_w<<<2 * 256 / 4, 256, 0, stream>>>(Wl1, Wr1, Wp1, 256);
    convert_w<<<2 * 256 / 4, 256, 0, stream>>>(Wl2, Wr2, Wp2, 256);

    int cx = n * 128;
    f32_to_bf16<<<(cx / 8 + 255) / 256, 256, 0, stream>>>(x, xb, cx);

    int gemm_grid = ((n + 63) / 64) * 2;   // 1564
    // layer 0: C=128 -> 256
    agg_bf16<128><<<(n + 15) / 16, 256, 0, stream>>>(xb, rowptr, csr, invd, aggb, n);
    gemm_direct<128><<<gemm_grid, 256, 0, stream>>>(aggb, xb, Wp0, bl0, (float*)nullptr, h0b, n);
    // layer 1: 256 -> 256
    agg_bf16<256><<<(n + 7) / 8, 256, 0, stream>>>(h0b, rowptr, csr, invd, aggb, n);
    gemm_direct<256><<<gemm_grid, 256, 0, stream>>>(aggb, h0b, Wp1, bl1, (float*)nullptr, h1b, n);
    // layer 2: 256 -> 256 (fp32 output to d_out)
    agg_bf16<256><<<(n + 7) / 8, 256, 0, stream>>>(h1b, rowptr, csr, invd, aggb, n);
    gemm_direct<256><<<gemm_grid, 256, 0, stream>>>(aggb, h1b, Wp2, bl2, (float*)d_out, (uint16_t*)nullptr, n);
}

// Round 10
// 443.766 us; speedup vs baseline: 1.0501x; 1.0501x over previous
//
#include <hip/hip_runtime.h>
#include <cstdint>
#include <cstddef>

// GraphSAGE 3-layer, mean aggregation.
// R10: return to R6's winning GEMM structure (LDS A-tile, W global->reg,
// 64x256 block) with the R8 insight that A can be the bf16 copy (2 mfma/frag,
// absmax-verified) — so A staging is ONE global_load_lds(16B)/thread/step
// (zero VGPR cost) — and a zero-register double-buffer: loadW(s), prefetch
// A[s+1] into buf^1, mfma(s) (vmcnt(1) leaves prefetch in flight), barrier.
// LDS chunk swizzle via pre-swizzled global source (slot=(tid&3)^((r>>1)&3))
// -> ds_read_b128 conflicts <=2-way (free). launch_bounds(256,3) (R6's (256,2)
// was itself the occupancy cap).
// R7/R9 lesson: register-held pipelines lose (VGPR pressure or compiler
// re-scheduling); direct-to-LDS prefetch is the only free depth.

typedef __bf16 bf16x8 __attribute__((ext_vector_type(8)));
typedef __bf16 bf16x4 __attribute__((ext_vector_type(4)));
typedef float  f32x4  __attribute__((ext_vector_type(4)));

static inline size_t align_up(size_t x, size_t a) { return (x + a - 1) / a * a; }

__device__ __forceinline__ void gload_lds16(const void* g, void* l) {
    __builtin_amdgcn_global_load_lds(
        (const __attribute__((address_space(1))) void*)g,
        (__attribute__((address_space(3))) void*)l, 16, 0, 0);
}

__global__ void deg_kernel(const int* __restrict__ dst, int* __restrict__ deg, int E) {
    int i = blockIdx.x * blockDim.x + threadIdx.x;
    if (i < E) atomicAdd(&deg[dst[i]], 1);
}

// ---- 3-phase scan: deg -> rowptr (exclusive), cursor, inv_deg ----
__global__ void scan_a(const int* __restrict__ deg, int* __restrict__ blocksums, int n) {
    __shared__ int ts[256];
    int t = threadIdx.x;
    int base = blockIdx.x * 1024 + t * 4;
    int s = 0;
    #pragma unroll
    for (int j = 0; j < 4; ++j) if (base + j < n) s += deg[base + j];
    ts[t] = s;
    __syncthreads();
    #pragma unroll
    for (int off = 128; off >= 1; off >>= 1) {
        if (t < off) ts[t] += ts[t + off];
        __syncthreads();
    }
    if (t == 0) blocksums[blockIdx.x] = ts[0];
}

__global__ void scan_b(const int* __restrict__ blocksums, int* __restrict__ blockoff,
                       int NB, int* __restrict__ rowptr_n) {
    __shared__ int ts[256];
    int t = threadIdx.x;
    int v = (t < NB) ? blocksums[t] : 0;
    ts[t] = v;
    __syncthreads();
    for (int off = 1; off < 256; off <<= 1) {
        int u = (t >= off) ? ts[t - off] : 0;
        __syncthreads();
        ts[t] += u;
        __syncthreads();
    }
    if (t < NB) blockoff[t] = ts[t] - v;
    if (t == 255) *rowptr_n = ts[255];
}

__global__ void scan_c(const int* __restrict__ deg, const int* __restrict__ blockoff,
                       int* __restrict__ rowptr, int* __restrict__ cursor,
                       float* __restrict__ inv_deg, int n) {
    __shared__ int ts[256];
    int t = threadIdx.x;
    int base = blockIdx.x * 1024 + t * 4;
    int d[4];
    int s = 0;
    #pragma unroll
    for (int j = 0; j < 4; ++j) {
        d[j] = (base + j < n) ? deg[base + j] : 0;
        s += d[j];
    }
    ts[t] = s;
    __syncthreads();
    for (int off = 1; off < 256; off <<= 1) {
        int u = (t >= off) ? ts[t - off] : 0;
        __syncthreads();
        ts[t] += u;
        __syncthreads();
    }
    int ex = ts[t] - s + blockoff[blockIdx.x];
    #pragma unroll
    for (int j = 0; j < 4; ++j) {
        if (base + j < n) {
            rowptr[base + j] = ex;
            cursor[base + j] = ex;
            inv_deg[base + j] = d[j] > 0 ? 1.0f / (float)d[j] : 0.0f;
            ex += d[j];
        }
    }
}

__global__ void fill_kernel(const int* __restrict__ src, const int* __restrict__ dst,
                            int* __restrict__ cursor, int* __restrict__ csr, int E) {
    int i = blockIdx.x * blockDim.x + threadIdx.x;
    if (i < E) {
        int p = atomicAdd(&cursor[dst[i]], 1);
        csr[p] = src[i];
    }
}

// fp32 -> bf16 (RTNE) convert, 8 elems/thread.
__global__ void f32_to_bf16(const float* __restrict__ in, uint16_t* __restrict__ out, int count) {
    int i = (blockIdx.x * blockDim.x + threadIdx.x) * 8;
    if (i >= count) return;
    float4 v0 = *(const float4*)(in + i);
    float4 v1 = *(const float4*)(in + i + 4);
    bf16x8 o;
    o[0] = (__bf16)v0.x; o[1] = (__bf16)v0.y; o[2] = (__bf16)v0.z; o[3] = (__bf16)v0.w;
    o[4] = (__bf16)v1.x; o[5] = (__bf16)v1.y; o[6] = (__bf16)v1.z; o[7] = (__bf16)v1.w;
    *(bf16x8*)(out + i) = o;
}

__device__ inline void addq(float* a, uint32_t u0, uint32_t u1, uint32_t u2, uint32_t u3) {
    uint32_t u[4] = {u0, u1, u2, u3};
    #pragma unroll
    for (int i = 0; i < 4; ++i) {
        a[2 * i]     += __uint_as_float(u[i] << 16);
        a[2 * i + 1] += __uint_as_float(u[i] & 0xffff0000u);
    }
}

// bf16 gather aggregation: C/8 lanes per node, 16B (8 bf16) per lane.
template<int C>
__global__ void agg_bf16(const uint16_t* __restrict__ hb, const int* __restrict__ rowptr,
                         const int* __restrict__ csr, const float* __restrict__ inv_deg,
                         uint16_t* __restrict__ aggb, int n) {
    constexpr int LPN = C / 8;
    constexpr int NPB = 256 / LPN;
    int node = blockIdx.x * NPB + (int)(threadIdx.x / LPN);
    if (node >= n) return;
    int sub = threadIdx.x % LPN;
    int b = rowptr[node], e = rowptr[node + 1];
    float acc[8] = {0.f, 0.f, 0.f, 0.f, 0.f, 0.f, 0.f, 0.f};
    const uint4* h4 = (const uint4*)hb;
    int k = b;
    for (; k + 3 < e; k += 4) {
        int s0 = csr[k], s1 = csr[k + 1], s2 = csr[k + 2], s3 = csr[k + 3];
        uint4 q0 = h4[(size_t)s0 * LPN + sub];
        uint4 q1 = h4[(size_t)s1 * LPN + sub];
        uint4 q2 = h4[(size_t)s2 * LPN + sub];
        uint4 q3 = h4[(size_t)s3 * LPN + sub];
        addq(acc, q0.x, q0.y, q0.z, q0.w);
        addq(acc, q1.x, q1.y, q1.z, q1.w);
        addq(acc, q2.x, q2.y, q2.z, q2.w);
        addq(acc, q3.x, q3.y, q3.z, q3.w);
    }
    for (; k < e; ++k) {
        uint4 q = h4[(size_t)csr[k] * LPN + sub];
        addq(acc, q.x, q.y, q.z, q.w);
    }
    float id = inv_deg[node];
    bf16x8 o;
    #pragma unroll
    for (int j = 0; j < 8; ++j) o[j] = (__bf16)(acc[j] * id);
    *(bf16x8*)(aggb + (size_t)node * C + sub * 8) = o;
}

// Pre-convert W = [Wl; Wr] into per-k-step bf16 hi/lo planes.
// Step s (BK=32): [hi 16KB][lo 16KB]; element (k,n) at byte n*64 + (k%32)*2.
__global__ void convert_w(const float* __restrict__ Wl, const float* __restrict__ Wr,
                          uint8_t* __restrict__ Wpre, int K1) {
    int n = threadIdx.x;
    int kbase = blockIdx.x * 4;
    bf16x4 hi4, lo4;
    #pragma unroll
    for (int j = 0; j < 4; ++j) {
        int k = kbase + j;
        float w = (k < K1) ? Wl[(size_t)k * 256 + n] : Wr[(size_t)(k - K1) * 256 + n];
        __bf16 h = (__bf16)w;
        __bf16 l = (__bf16)(w - (float)h);
        hi4[j] = h;
        lo4[j] = l;
    }
    int s = kbase >> 5;
    int kk = kbase & 31;
    uint32_t byte = (uint32_t)(n * 64 + kk * 2);
    *(bf16x4*)(Wpre + (size_t)s * 32768 + byte) = hi4;
    *(bf16x4*)(Wpre + (size_t)s * 32768 + 16384 + byte) = lo4;
}

__device__ inline uint16_t f2bf(float f) {
    __bf16 h = (__bf16)f;
    union { __bf16 b; uint16_t u; } c;
    c.b = h;
    return c.u;
}

// Fused GEMM: out = relu([A1 | A2] @ (Whi+Wlo) + bias), A row-major bf16.
// 64 rows x 256 cols per block, 4 waves. Per k-step: A tile (64x32 bf16, 4KB)
// via one global_load_lds(16B)/thread into the spare buffer (prefetch, zero
// regs); W frags global->reg; 32 MFMAs; one barrier.
template<int K1>
__global__ __launch_bounds__(256, 3)
void gemm_mfma(const uint16_t* __restrict__ A1, const uint16_t* __restrict__ A2,
               const uint8_t* __restrict__ Wpre, const float* __restrict__ bias,
               float* __restrict__ out, uint16_t* __restrict__ outb, int n) {
    constexpr int S1 = K1 / 32;
    constexpr int NT = 2 * S1;          // 8 or 16
    __shared__ __align__(16) uint8_t lds[2][4096];

    const int tid = threadIdx.x;
    const int l = tid & 63;
    const int w = tid >> 6;
    const int lr = l & 15;
    const int lg = l >> 4;
    const int row0 = blockIdx.x * 64;
    const int wn = w * 64;

    f32x4 acc[4][4];
    #pragma unroll
    for (int mt = 0; mt < 4; ++mt)
        #pragma unroll
        for (int nt = 0; nt < 4; ++nt)
            acc[mt][nt] = (f32x4)(0.f);

    // A fragment read offsets (swizzled): row r, slot lg^((r>>1)&3)
    uint32_t abyte[4];
    #pragma unroll
    for (int mt = 0; mt < 4; ++mt) {
        int r = mt * 16 + lr;
        abyte[mt] = (uint32_t)(r * 64 + ((lg ^ ((r >> 1) & 3)) << 4));
    }
    // W fragment offsets within a k-step plane
    uint32_t bbyte[4];
    #pragma unroll
    for (int nt = 0; nt < 4; ++nt)
        bbyte[nt] = (uint32_t)((wn + nt * 16 + lr) * 64 + lg * 16);

    // staging map: thread tid -> LDS chunk tid (linear); source chunk
    // pre-swizzled so LDS slot s' of row r holds k-quad s'^((r>>1)&3).
    const int sr = tid >> 2;                       // row 0..63
    const int kq = (tid & 3) ^ ((sr >> 2) & 3);    // note: (r>>1)&3 on 16-row frag rows
    // careful: swizzle key must match abyte's ((r>>1)&3) -> recompute correctly:
    const int kq2 = (tid & 3) ^ ((sr >> 1) & 3);
    (void)kq;

    auto issueA = [&](int s, int buf) {
        const uint16_t* __restrict__ A = (s < S1) ? A1 : A2;
        int kl = ((s < S1) ? s : s - S1) * 32;
        const uint16_t* g = A + (size_t)(row0 + sr) * K1 + kl + kq2 * 8;
        gload_lds16(g, &lds[buf][w * 1024]);
    };

    bf16x8 bh[4], bl_[4];
    auto loadW = [&](int s) {
        const uint8_t* __restrict__ Ws = Wpre + (size_t)s * 32768;
        #pragma unroll
        for (int nt = 0; nt < 4; ++nt) {
            bh[nt]  = *(const bf16x8*)(Ws + bbyte[nt]);
            bl_[nt] = *(const bf16x8*)(Ws + 16384 + bbyte[nt]);
        }
    };
    auto domfma = [&](int buf) {
        #pragma unroll
        for (int mt = 0; mt < 4; ++mt) {
            bf16x8 a = *(const bf16x8*)(&lds[buf][abyte[mt]]);
            #pragma unroll
            for (int nt = 0; nt < 4; ++nt) {
                acc[mt][nt] = __builtin_amdgcn_mfma_f32_16x16x32_bf16(a, bh[nt],  acc[mt][nt], 0, 0, 0);
                acc[mt][nt] = __builtin_amdgcn_mfma_f32_16x16x32_bf16(a, bl_[nt], acc[mt][nt], 0, 0, 0);
            }
        }
    };

    issueA(0, 0);
    __syncthreads();                      // vmcnt(0) drain -> buf0 ready
    #pragma unroll 1
    for (int s = 0; s < NT - 2; s += 2) {
        loadW(s);                         // W first (older in vmcnt queue)
        issueA(s + 1, 1);                 // prefetch stays in flight over mfma
        domfma(0);
        __syncthreads();
        loadW(s + 1);
        issueA(s + 2, 0);
        domfma(1);
        __syncthreads();
    }
    loadW(NT - 2);
    issueA(NT - 1, 1);
    domfma(0);
    __syncthreads();
    loadW(NT - 1);
    domfma(1);

    // epilogue: D row = mt*16 + lg*4 + rr, col = wn + nt*16 + lr (m89-verified)
    #pragma unroll
    for (int nt = 0; nt < 4; ++nt) {
        int col = wn + nt * 16 + lr;
        float bv = bias[col];
        #pragma unroll
        for (int mt = 0; mt < 4; ++mt) {
            #pragma unroll
            for (int rr = 0; rr < 4; ++rr) {
                int grow = row0 + mt * 16 + lg * 4 + rr;
                if (grow < n) {
                    float v = fmaxf(acc[mt][nt][rr] + bv, 0.f);
                    if (out)  out[(size_t)grow * 256 + col] = v;
                    if (outb) outb[(size_t)grow * 256 + col] = f2bf(v);
                }
            }
        }
    }
}

extern "C" void kernel_launch(void* const* d_in, const int* in_sizes, int n_in,
                              void* d_out, int out_size, void* d_ws, size_t ws_size,
                              hipStream_t stream) {
    const float* x   = (const float*)d_in[0];
    const int* edge  = (const int*)d_in[1];
    const float* Wl0 = (const float*)d_in[2];
    const float* bl0 = (const float*)d_in[3];
    const float* Wr0 = (const float*)d_in[4];
    const float* Wl1 = (const float*)d_in[5];
    const float* bl1 = (const float*)d_in[6];
    const float* Wr1 = (const float*)d_in[7];
    const float* Wl2 = (const float*)d_in[8];
    const float* bl2 = (const float*)d_in[9];
    const float* Wr2 = (const float*)d_in[10];

    int n = in_sizes[0] / 128;   // 50000
    int E = in_sizes[1] / 2;     // 800000
    int npad = n + 64;
    const int* src = edge;
    const int* dst = edge + E;

    char* wptr = (char*)d_ws;
    auto alloc = [&](size_t bytes) { char* p = wptr; wptr += align_up(bytes, 256); return p; };
    int*      deg    = (int*)alloc((size_t)n * 4);
    int*      rowptr = (int*)alloc(((size_t)n + 1) * 4);
    int*      cursor = (int*)alloc((size_t)n * 4);
    int*      csr    = (int*)alloc((size_t)E * 4);
    float*    invd   = (float*)alloc((size_t)n * 4);
    int*      bsums  = (int*)alloc(256 * 4);
    int*      boff   = (int*)alloc(256 * 4);
    uint8_t*  Wp0    = (uint8_t*)alloc(8 * 32768);
    uint8_t*  Wp1    = (uint8_t*)alloc(16 * 32768);
    uint8_t*  Wp2    = (uint8_t*)alloc(16 * 32768);
    uint16_t* xb     = (uint16_t*)alloc((size_t)npad * 128 * 2);
    uint16_t* aggb   = (uint16_t*)alloc((size_t)npad * 256 * 2);
    uint16_t* h0b    = (uint16_t*)alloc((size_t)npad * 256 * 2);
    uint16_t* h1b    = (uint16_t*)alloc((size_t)npad * 256 * 2);

    int NB = (n + 1023) / 1024;
    hipMemsetAsync(deg, 0, (size_t)n * 4, stream);
    deg_kernel<<<(E + 255) / 256, 256, 0, stream>>>(dst, deg, E);
    scan_a<<<NB, 256, 0, stream>>>(deg, bsums, n);
    scan_b<<<1, 256, 0, stream>>>(bsums, boff, NB, rowptr + n);
    scan_c<<<NB, 256, 0, stream>>>(deg, boff, rowptr, cursor, invd, n);
    fill_kernel<<<(E + 255) / 256, 256, 0, stream>>>(src, dst, cursor, csr, E);

    convert_w<<<2 * 128 / 4, 256, 0, stream>>>(Wl0, Wr0, Wp0, 128);
    convert_w<<<2 * 256 / 4, 256, 0, stream>>>(Wl1, Wr1, Wp1, 256);
    convert_w<<<2 * 256 / 4, 256, 0, stream>>>(Wl2, Wr2, Wp2, 256);

    int cx = n * 128;
    f32_to_bf16<<<(cx / 8 + 255) / 256, 256, 0, stream>>>(x, xb, cx);

    int gemm_grid = (n + 63) / 64;   // 782
    // layer 0: C=128 -> 256
    agg_bf16<128><<<(n + 15) / 16, 256, 0, stream>>>(xb, rowptr, csr, invd, aggb, n);
    gemm_mfma<128><<<gemm_grid, 256, 0, stream>>>(aggb, xb, Wp0, bl0, (float*)nullptr, h0b, n);
    // layer 1: 256 -> 256
    agg_bf16<256><<<(n + 7) / 8, 256, 0, stream>>>(h0b, rowptr, csr, invd, aggb, n);
    gemm_mfma<256><<<gemm_grid, 256, 0, stream>>>(aggb, h0b, Wp1, bl1, (float*)nullptr, h1b, n);
    // layer 2: 256 -> 256 (fp32 output to d_out)
    agg_bf16<256><<<(n + 7) / 8, 256, 0, stream>>>(h1b, rowptr, csr, invd, aggb, n);
    gemm_mfma<256><<<gemm_grid, 256, 0, stream>>>(aggb, h1b, Wp2, bl2, (float*)d_out, (uint16_t*)nullptr, n);
}

// Round 11
// 409.722 us; speedup vs baseline: 1.1374x; 1.0831x over previous
//
#include <hip/hip_runtime.h>
#include <cstdint>
#include <cstddef>

// GraphSAGE 3-layer, mean aggregation.
// R11: full m97-style GEMM pipeline. R6-R10 all exposed W's L2 latency
// serially per k-step (MfmaUtil 12-23%). Now BOTH operands stage via
// global_load_lds into double-buffered LDS (A 4KB + W 32KB per buf, 72KB
// total, 2 blocks/CU); per step: stage(s+1, buf^1) issued BEFORE
// ds_read+MFMA(buf); ONE barrier per step drains the prefetch after MFMA.
// Wpre re-layouted fragment-major ([col-group][lane][16B] per plane) so W
// staging is a linear copy and W ds_read_b128 is the conflict-free
// lane->consecutive-16B pattern. A staging keeps R10's pre-swizzled source
// (2-way conflicts = free).
// Lessons kept: bf16 A operand (R8, absmax-verified), W hi/lo split (R2),
// bf16 gather agg (R4), 3-phase scan (R3).

typedef __bf16 bf16x8 __attribute__((ext_vector_type(8)));
typedef __bf16 bf16x4 __attribute__((ext_vector_type(4)));
typedef float  f32x4  __attribute__((ext_vector_type(4)));

static inline size_t align_up(size_t x, size_t a) { return (x + a - 1) / a * a; }

__device__ __forceinline__ void gload_lds16(const void* g, void* l) {
    __builtin_amdgcn_global_load_lds(
        (const __attribute__((address_space(1))) void*)g,
        (__attribute__((address_space(3))) void*)l, 16, 0, 0);
}

__global__ void deg_kernel(const int* __restrict__ dst, int* __restrict__ deg, int E) {
    int i = blockIdx.x * blockDim.x + threadIdx.x;
    if (i < E) atomicAdd(&deg[dst[i]], 1);
}

// ---- 3-phase scan: deg -> rowptr (exclusive), cursor, inv_deg ----
__global__ void scan_a(const int* __restrict__ deg, int* __restrict__ blocksums, int n) {
    __shared__ int ts[256];
    int t = threadIdx.x;
    int base = blockIdx.x * 1024 + t * 4;
    int s = 0;
    #pragma unroll
    for (int j = 0; j < 4; ++j) if (base + j < n) s += deg[base + j];
    ts[t] = s;
    __syncthreads();
    #pragma unroll
    for (int off = 128; off >= 1; off >>= 1) {
        if (t < off) ts[t] += ts[t + off];
        __syncthreads();
    }
    if (t == 0) blocksums[blockIdx.x] = ts[0];
}

__global__ void scan_b(const int* __restrict__ blocksums, int* __restrict__ blockoff,
                       int NB, int* __restrict__ rowptr_n) {
    __shared__ int ts[256];
    int t = threadIdx.x;
    int v = (t < NB) ? blocksums[t] : 0;
    ts[t] = v;
    __syncthreads();
    for (int off = 1; off < 256; off <<= 1) {
        int u = (t >= off) ? ts[t - off] : 0;
        __syncthreads();
        ts[t] += u;
        __syncthreads();
    }
    if (t < NB) blockoff[t] = ts[t] - v;
    if (t == 255) *rowptr_n = ts[255];
}

__global__ void scan_c(const int* __restrict__ deg, const int* __restrict__ blockoff,
                       int* __restrict__ rowptr, int* __restrict__ cursor,
                       float* __restrict__ inv_deg, int n) {
    __shared__ int ts[256];
    int t = threadIdx.x;
    int base = blockIdx.x * 1024 + t * 4;
    int d[4];
    int s = 0;
    #pragma unroll
    for (int j = 0; j < 4; ++j) {
        d[j] = (base + j < n) ? deg[base + j] : 0;
        s += d[j];
    }
    ts[t] = s;
    __syncthreads();
    for (int off = 1; off < 256; off <<= 1) {
        int u = (t >= off) ? ts[t - off] : 0;
        __syncthreads();
        ts[t] += u;
        __syncthreads();
    }
    int ex = ts[t] - s + blockoff[blockIdx.x];
    #pragma unroll
    for (int j = 0; j < 4; ++j) {
        if (base + j < n) {
            rowptr[base + j] = ex;
            cursor[base + j] = ex;
            inv_deg[base + j] = d[j] > 0 ? 1.0f / (float)d[j] : 0.0f;
            ex += d[j];
        }
    }
}

__global__ void fill_kernel(const int* __restrict__ src, const int* __restrict__ dst,
                            int* __restrict__ cursor, int* __restrict__ csr, int E) {
    int i = blockIdx.x * blockDim.x + threadIdx.x;
    if (i < E) {
        int p = atomicAdd(&cursor[dst[i]], 1);
        csr[p] = src[i];
    }
}

// fp32 -> bf16 (RTNE) convert, 8 elems/thread.
__global__ void f32_to_bf16(const float* __restrict__ in, uint16_t* __restrict__ out, int count) {
    int i = (blockIdx.x * blockDim.x + threadIdx.x) * 8;
    if (i >= count) return;
    float4 v0 = *(const float4*)(in + i);
    float4 v1 = *(const float4*)(in + i + 4);
    bf16x8 o;
    o[0] = (__bf16)v0.x; o[1] = (__bf16)v0.y; o[2] = (__bf16)v0.z; o[3] = (__bf16)v0.w;
    o[4] = (__bf16)v1.x; o[5] = (__bf16)v1.y; o[6] = (__bf16)v1.z; o[7] = (__bf16)v1.w;
    *(bf16x8*)(out + i) = o;
}

__device__ inline void addq(float* a, uint32_t u0, uint32_t u1, uint32_t u2, uint32_t u3) {
    uint32_t u[4] = {u0, u1, u2, u3};
    #pragma unroll
    for (int i = 0; i < 4; ++i) {
        a[2 * i]     += __uint_as_float(u[i] << 16);
        a[2 * i + 1] += __uint_as_float(u[i] & 0xffff0000u);
    }
}

// bf16 gather aggregation: C/8 lanes per node, 16B (8 bf16) per lane.
template<int C>
__global__ void agg_bf16(const uint16_t* __restrict__ hb, const int* __restrict__ rowptr,
                         const int* __restrict__ csr, const float* __restrict__ inv_deg,
                         uint16_t* __restrict__ aggb, int n) {
    constexpr int LPN = C / 8;
    constexpr int NPB = 256 / LPN;
    int node = blockIdx.x * NPB + (int)(threadIdx.x / LPN);
    if (node >= n) return;
    int sub = threadIdx.x % LPN;
    int b = rowptr[node], e = rowptr[node + 1];
    float acc[8] = {0.f, 0.f, 0.f, 0.f, 0.f, 0.f, 0.f, 0.f};
    const uint4* h4 = (const uint4*)hb;
    int k = b;
    for (; k + 3 < e; k += 4) {
        int s0 = csr[k], s1 = csr[k + 1], s2 = csr[k + 2], s3 = csr[k + 3];
        uint4 q0 = h4[(size_t)s0 * LPN + sub];
        uint4 q1 = h4[(size_t)s1 * LPN + sub];
        uint4 q2 = h4[(size_t)s2 * LPN + sub];
        uint4 q3 = h4[(size_t)s3 * LPN + sub];
        addq(acc, q0.x, q0.y, q0.z, q0.w);
        addq(acc, q1.x, q1.y, q1.z, q1.w);
        addq(acc, q2.x, q2.y, q2.z, q2.w);
        addq(acc, q3.x, q3.y, q3.z, q3.w);
    }
    for (; k < e; ++k) {
        uint4 q = h4[(size_t)csr[k] * LPN + sub];
        addq(acc, q.x, q.y, q.z, q.w);
    }
    float id = inv_deg[node];
    bf16x8 o;
    #pragma unroll
    for (int j = 0; j < 8; ++j) o[j] = (__bf16)(acc[j] * id);
    *(bf16x8*)(aggb + (size_t)node * C + sub * 8) = o;
}

// Pre-convert W = [Wl; Wr] into per-k-step FRAGMENT-MAJOR bf16 hi/lo planes.
// Step s (BK=32), plane 16KB: col-group cg (0..15) x lane l (0..63) x 16B.
// The 16B at (cg, l) = cols cg*16+(l&15), k-quad (l>>4)*8..+7 (k-ascending).
// -> wave fragment ds_read_b128: lane l reads byte cg*1024 + l*16
//    (consecutive 16B per lane = conflict-free, m134 pattern);
//    staging is a linear chunk copy.
__global__ void convert_w(const float* __restrict__ Wl, const float* __restrict__ Wr,
                          uint8_t* __restrict__ Wpre, int K1) {
    int c = threadIdx.x;        // col 0..255
    int kbase = blockIdx.x * 4; // 4 consecutive k
    bf16x4 hi4, lo4;
    #pragma unroll
    for (int j = 0; j < 4; ++j) {
        int k = kbase + j;
        float w = (k < K1) ? Wl[(size_t)k * 256 + c] : Wr[(size_t)(k - K1) * 256 + c];
        __bf16 h = (__bf16)w;
        __bf16 l = (__bf16)(w - (float)h);
        hi4[j] = h;
        lo4[j] = l;
    }
    int s = kbase >> 5;
    int kk = kbase & 31;                         // 0,4,...,28
    int lane = (c & 15) + ((kk >> 3) << 4);      // 0..63
    uint32_t byte = (uint32_t)(c >> 4) * 1024 + (uint32_t)lane * 16 + (uint32_t)(kk & 7) * 2;
    *(bf16x4*)(Wpre + (size_t)s * 32768 + byte) = hi4;
    *(bf16x4*)(Wpre + (size_t)s * 32768 + 16384 + byte) = lo4;
}

__device__ inline uint16_t f2bf(float f) {
    __bf16 h = (__bf16)f;
    union { __bf16 b; uint16_t u; } c;
    c.b = h;
    return c.u;
}

// Fused GEMM: out = relu([A1 | A2] @ (Whi+Wlo) + bias), A row-major bf16.
// 64 rows x 256 cols per block, 4 waves. m97 pipeline: stage(s+1, buf^1) via
// global_load_lds (A 1 + W 8 insts/thread) issued before ds_read+MFMA of
// step s; one barrier per step drains the prefetch after the MFMAs.
template<int K1>
__global__ __launch_bounds__(256, 2)
void gemm_mfma(const uint16_t* __restrict__ A1, const uint16_t* __restrict__ A2,
               const uint8_t* __restrict__ Wpre, const float* __restrict__ bias,
               float* __restrict__ out, uint16_t* __restrict__ outb, int n) {
    constexpr int S1 = K1 / 32;
    constexpr int NT = 2 * S1;          // 8 or 16
    __shared__ __align__(16) uint8_t ldsA[2][4096];
    __shared__ __align__(16) uint8_t ldsW[2][32768];

    const int tid = threadIdx.x;
    const int l = tid & 63;
    const int w = tid >> 6;
    const int lr = l & 15;
    const int lg = l >> 4;
    const int row0 = blockIdx.x * 64;
    const int wn = w * 64;

    f32x4 acc[4][4];
    #pragma unroll
    for (int mt = 0; mt < 4; ++mt)
        #pragma unroll
        for (int nt = 0; nt < 4; ++nt)
            acc[mt][nt] = (f32x4)(0.f);

    // A fragment read offsets (swizzled): row r, slot lg^((r>>1)&3)
    uint32_t abyte[4];
    #pragma unroll
    for (int mt = 0; mt < 4; ++mt) {
        int r = mt * 16 + lr;
        abyte[mt] = (uint32_t)(r * 64 + ((lg ^ ((r >> 1) & 3)) << 4));
    }
    // W fragment read offsets (fragment-major, conflict-free)
    uint32_t wrbyte[4];
    #pragma unroll
    for (int nt = 0; nt < 4; ++nt)
        wrbyte[nt] = (uint32_t)((w * 4 + nt) * 1024 + l * 16);

    // A staging source map (pre-swizzled so LDS slot matches abyte)
    const int sr = tid >> 2;                       // row 0..63
    const int kq2 = (tid & 3) ^ ((sr >> 1) & 3);   // k-quad for this LDS slot
    const size_t aoff_t = (size_t)(row0 + sr) * K1 + (size_t)kq2 * 8;
    // W staging source offset for this thread's 8 chunks (chunk = w*8+i)
    const uint32_t wsrc_t = (uint32_t)((w * 8) * 64 + l) * 16;

    auto stage = [&](int s, int buf) {
        const uint16_t* __restrict__ A = (s < S1) ? A1 : A2;
        int kl = ((s < S1) ? s : s - S1) * 32;
        gload_lds16(A + aoff_t + kl, &ldsA[buf][w * 1024]);
        const uint8_t* __restrict__ Ws = Wpre + (size_t)s * 32768 + wsrc_t;
        #pragma unroll
        for (int i = 0; i < 8; ++i)
            gload_lds16(Ws + i * 1024, &ldsW[buf][(w * 8 + i) * 1024]);
    };

    auto domfma = [&](int buf) {
        bf16x8 bh[4], bl_[4];
        #pragma unroll
        for (int nt = 0; nt < 4; ++nt) {
            bh[nt]  = *(const bf16x8*)(&ldsW[buf][wrbyte[nt]]);
            bl_[nt] = *(const bf16x8*)(&ldsW[buf][16384 + wrbyte[nt]]);
        }
        #pragma unroll
        for (int mt = 0; mt < 4; ++mt) {
            bf16x8 a = *(const bf16x8*)(&ldsA[buf][abyte[mt]]);
            #pragma unroll
            for (int nt = 0; nt < 4; ++nt) {
                acc[mt][nt] = __builtin_amdgcn_mfma_f32_16x16x32_bf16(a, bh[nt],  acc[mt][nt], 0, 0, 0);
                acc[mt][nt] = __builtin_amdgcn_mfma_f32_16x16x32_bf16(a, bl_[nt], acc[mt][nt], 0, 0, 0);
            }
        }
    };

    stage(0, 0);
    __syncthreads();                    // drains vmcnt -> buf0 ready
    #pragma unroll 1
    for (int s = 0; s < NT; ++s) {
        int buf = s & 1;
        if (s + 1 < NT) stage(s + 1, buf ^ 1);   // in flight over MFMAs
        domfma(buf);
        __syncthreads();                // drain prefetch + protect reuse
    }

    // epilogue: D row = mt*16 + lg*4 + rr, col = wn + nt*16 + lr (m89-verified)
    #pragma unroll
    for (int nt = 0; nt < 4; ++nt) {
        int col = wn + nt * 16 + lr;
        float bv = bias[col];
        #pragma unroll
        for (int mt = 0; mt < 4; ++mt) {
            #pragma unroll
            for (int rr = 0; rr < 4; ++rr) {
                int grow = row0 + mt * 16 + lg * 4 + rr;
                if (grow < n) {
                    float v = fmaxf(acc[mt][nt][rr] + bv, 0.f);
                    if (out)  out[(size_t)grow * 256 + col] = v;
                    if (outb) outb[(size_t)grow * 256 + col] = f2bf(v);
                }
            }
        }
    }
}

extern "C" void kernel_launch(void* const* d_in, const int* in_sizes, int n_in,
                              void* d_out, int out_size, void* d_ws, size_t ws_size,
                              hipStream_t stream) {
    const float* x   = (const float*)d_in[0];
    const int* edge  = (const int*)d_in[1];
    const float* Wl0 = (const float*)d_in[2];
    const float* bl0 = (const float*)d_in[3];
    const float* Wr0 = (const float*)d_in[4];
    const float* Wl1 = (const float*)d_in[5];
    const float* bl1 = (const float*)d_in[6];
    const float* Wr1 = (const float*)d_in[7];
    const float* Wl2 = (const float*)d_in[8];
    const float* bl2 = (const float*)d_in[9];
    const float* Wr2 = (const float*)d_in[10];

    int n = in_sizes[0] / 128;   // 50000
    int E = in_sizes[1] / 2;     // 800000
    int npad = n + 64;
    const int* src = edge;
    const int* dst = edge + E;

    char* wptr = (char*)d_ws;
    auto alloc = [&](size_t bytes) { char* p = wptr; wptr += align_up(bytes, 256); return p; };
    int*      deg    = (int*)alloc((size_t)n * 4);
    int*      rowptr = (int*)alloc(((size_t)n + 1) * 4);
    int*      cursor = (int*)alloc((size_t)n * 4);
    int*      csr    = (int*)alloc((size_t)E * 4);
    float*    invd   = (float*)alloc((size_t)n * 4);
    int*      bsums  = (int*)alloc(256 * 4);
    int*      boff   = (int*)alloc(256 * 4);
    uint8_t*  Wp0    = (uint8_t*)alloc(8 * 32768);
    uint8_t*  Wp1    = (uint8_t*)alloc(16 * 32768);
    uint8_t*  Wp2    = (uint8_t*)alloc(16 * 32768);
    uint16_t* xb     = (uint16_t*)alloc((size_t)npad * 128 * 2);
    uint16_t* aggb   = (uint16_t*)alloc((size_t)npad * 256 * 2);
    uint16_t* h0b    = (uint16_t*)alloc((size_t)npad * 256 * 2);
    uint16_t* h1b    = (uint16_t*)alloc((size_t)npad * 256 * 2);

    int NB = (n + 1023) / 1024;
    hipMemsetAsync(deg, 0, (size_t)n * 4, stream);
    deg_kernel<<<(E + 255) / 256, 256, 0, stream>>>(dst, deg, E);
    scan_a<<<NB, 256, 0, stream>>>(deg, bsums, n);
    scan_b<<<1, 256, 0, stream>>>(bsums, boff, NB, rowptr + n);
    scan_c<<<NB, 256, 0, stream>>>(deg, boff, rowptr, cursor, invd, n);
    fill_kernel<<<(E + 255) / 256, 256, 0, stream>>>(src, dst, cursor, csr, E);

    convert_w<<<2 * 128 / 4, 256, 0, stream>>>(Wl0, Wr0, Wp0, 128);
    convert_w<<<2 * 256 / 4, 256, 0, stream>>>(Wl1, Wr1, Wp1, 256);
    convert_w<<<2 * 256 / 4, 256, 0, stream>>>(Wl2, Wr2, Wp2, 256);

    int cx = n * 128;
    f32_to_bf16<<<(cx / 8 + 255) / 256, 256, 0, stream>>>(x, xb, cx);

    int gemm_grid = (n + 63) / 64;   // 782
    // layer 0: C=128 -> 256
    agg_bf16<128><<<(n + 15) / 16, 256, 0, stream>>>(xb, rowptr, csr, invd, aggb, n);
    gemm_mfma<128><<<gemm_grid, 256, 0, stream>>>(aggb, xb, Wp0, bl0, (float*)nullptr, h0b, n);
    // layer 1: 256 -> 256
    agg_bf16<256><<<(n + 7) / 8, 256, 0, stream>>>(h0b, rowptr, csr, invd, aggb, n);
    gemm_mfma<256><<<gemm_grid, 256, 0, stream>>>(aggb, h0b, Wp1, bl1, (float*)nullptr, h1b, n);
    // layer 2: 256 -> 256 (fp32 output to d_out)
    agg_bf16<256><<<(n + 7) / 8, 256, 0, stream>>>(h1b, rowptr, csr, invd, aggb, n);
    gemm_mfma<256><<<gemm_grid, 256, 0, stream>>>(aggb, h1b, Wp2, bl2, (float*)d_out, (uint16_t*)nullptr, n);
}